// Round 10
// baseline (1668.699 us; speedup 1.0000x reference)
//
#include <hip/hip_runtime.h>
#include <hip/hip_bf16.h>

// Attention-augmented LSTM encoder. B=2048, T=128, N=128, H=256.
// softmax shift-invariance -> attention time-invariant; w_h/w_c/b_attn dead.
//
// Round 10 = round 9 (829us) + on-path shaving, same proven topology
// (256 blocks = 32-row x 64-hcol tiles, weights persistent in 192 VGPRs,
// relaxed sc0sc1 L3 exchange, per-wave u8 flags in one padded line):
//  1) own-column h-MFMAs (16/64) moved OFF the critical path: computed at
//     the loop tail for step t+1 from block-local hsh (available after the
//     cell barrier), alongside the wx-part MFMAs. On-path MFMA: 64 -> 48.
//  2) out1 stores moved AFTER the flag publish; their acks drain inside the
//     next poll's vmcnt(0).
//  3) cell writes hsh (export dependency) before osh.

#define B_ 2048
#define T_ 128
#define N_ 128
#define H_ 256
#define RG_ 64   // rowgroups of 32 rows

typedef float f32x4 __attribute__((ext_vector_type(4)));
typedef short bf16x8 __attribute__((ext_vector_type(8)));
typedef unsigned short u16;
typedef unsigned int u32;
typedef u32 u32x4 __attribute__((ext_vector_type(4)));

__device__ __forceinline__ u16 f2bf(float f) {
  unsigned int u = __float_as_uint(f);
  u += 0x7fffu + ((u >> 16) & 1u);   // RNE
  return (u16)(u >> 16);
}
__device__ __forceinline__ float sigm(float x) { return 1.f / (1.f + __expf(-x)); }
__device__ __forceinline__ float tanh_(float x) {
  float e = __expf(2.f * x);
  return 1.f - 2.f / (e + 1.f);
}

// device-coherent (L3) ops, relaxed (no cache-maintenance instructions)
__device__ __forceinline__ bf16x8 ld16_dev(const u16* p) {
  bf16x8 v;
  asm volatile("global_load_dwordx4 %0, %1, off sc0 sc1" : "=v"(v) : "v"(p));
  return v;
}
__device__ __forceinline__ void st16_dev(u16* p, bf16x8 v) {
  asm volatile("global_store_dwordx4 %0, %1, off sc0 sc1" :: "v"(p), "v"(v) : "memory");
}
__device__ __forceinline__ void st1_dev(unsigned char* p, u32 v) {
  asm volatile("global_store_byte %0, %1, off sc0 sc1" :: "v"(p), "v"(v) : "memory");
}
__device__ __forceinline__ u32x4 ld_flags(const unsigned char* p) {
  u32x4 f;
  asm volatile("global_load_dwordx4 %0, %1, off sc0 sc1\n\ts_waitcnt vmcnt(0)"
               : "=v"(f) : "v"(p) : "memory");
  return f;
}

// ---------------------------------------------------------------- kernel 1
__global__ __launch_bounds__(128) void attn_wx_kernel(
    const float* __restrict__ x, const float* __restrict__ w_attn,
    float* __restrict__ out0) {
  const int b = blockIdx.x;
  const int n = threadIdx.x;
  const float* xb = x + (size_t)b * (T_ * N_);
  __shared__ float red[N_];
  float xv[T_];
  float p = 0.f;
#pragma unroll
  for (int t = 0; t < T_; ++t) {
    xv[t] = xb[t * N_ + n];
    p += xv[t] * w_attn[2 * H_ + t];
  }
  red[n] = p;
  __syncthreads();
  float m = red[0];
  for (int i = 1; i < N_; ++i) m = fmaxf(m, red[i]);
  float e = __expf(p - m);
  __syncthreads();
  red[n] = e;
  __syncthreads();
  float s = 0.f;
  for (int i = 0; i < N_; ++i) s += red[i];
  const float a = e / s;
  float* ob = out0 + (size_t)b * (T_ * N_);
#pragma unroll
  for (int t = 0; t < T_; ++t) ob[t * N_ + n] = a * xv[t];
}

// ------------------------------------------------------- weight prepack
// frag(g16=0..15, q=0..3, kc=0..11) at ((g16*4+q)*12+kc)*512; elem j of lane l
// = W[q*256+g16*16+(l&15)][kc*32+((l>>4)<<3)+j], W = [w_ih | w_hh], K=384.
__global__ __launch_bounds__(256) void prepack_kernel(
    const float* __restrict__ w_ih, const float* __restrict__ w_hh,
    u16* __restrict__ wpk) {
  const int idx = blockIdx.x * 256 + threadIdx.x;  // 393216
  const int j = idx & 7;
  const int l = (idx >> 3) & 63;
  const int rest = idx >> 9;
  const int kc = rest % 12;
  const int wq = rest / 12;
  const int q = wq & 3;
  const int g16 = wq >> 2;
  const int grow = q * H_ + g16 * 16 + (l & 15);
  const int k = kc * 32 + ((l >> 4) << 3) + j;
  const float v = (k < N_) ? w_ih[(size_t)grow * N_ + k]
                           : w_hh[(size_t)grow * H_ + (k - N_)];
  wpk[idx] = f2bf(v);
}

// ---------------------------------------------------------------- kernel 2
__global__ __launch_bounds__(256, 1) void lstm_kernel(
    const float* __restrict__ wx,      // out0 f32 [B][T][N] (L3-resident)
    const u16* __restrict__ wpk,
    const float* __restrict__ b_ih, const float* __restrict__ b_hh,
    float* __restrict__ out1,          // f32 [B][T][H]
    u16* __restrict__ hx,              // [2][RG][16 frag][512 u16]
    unsigned char* __restrict__ flags) { // [RG][128B line; 16 u8 used]
  __shared__ u16 hsh[2][32][72];       // own 64 h-cols (bf16), ping-pong
  __shared__ float osh[2][32][68];     // h f32 staging for coalesced out1
  const int bid = blockIdx.x;
  const int rg = bid >> 2, cg = bid & 3;
  const int rb = rg * 32;
  const int tid  = threadIdx.x;
  const int w    = tid >> 6;           // wave 0..3
  const int lane = tid & 63;
  const int l15  = lane & 15;
  const int koff = (lane >> 4) << 3;
  const int g16  = cg * 4 + w;
  const int hcol = cg * 64 + w * 16 + l15;

  // persistent weights: 48 frags = 192 VGPRs
  bf16x8 wfrag[4][12];
  {
    const u16* wp = wpk + (size_t)(g16 * 48) * 512 + (size_t)lane * 8;
#pragma unroll
    for (int q = 0; q < 4; ++q)
#pragma unroll
      for (int kc = 0; kc < 12; ++kc)
        wfrag[q][kc] = *(const bf16x8*)(wp + (size_t)(q * 12 + kc) * 512);
  }
  float bias[4];
#pragma unroll
  for (int q = 0; q < 4; ++q)
    bias[q] = b_ih[q * H_ + hcol] + b_hh[q * H_ + hcol];
  float creg[2][4] = {};

  unsigned char* flrow  = flags + (size_t)rg * 128;
  unsigned char* myflag = flrow + cg * 4 + w;
  const int mtf = w >> 1, kclf = w & 1;   // fragment this wave exports

  // ---- prologue: wx(0) -> pf; acc = bias + wx-part(0)  (h(-1)=0)
  f32x4 pf[2][4][2];
  f32x4 acc[2][4];
#pragma unroll
  for (int mt = 0; mt < 2; ++mt)
#pragma unroll
    for (int kc = 0; kc < 4; ++kc) {
      const float* p = wx + (size_t)(rb + mt * 16 + l15) * (T_ * N_) + kc * 32 + koff;
      pf[mt][kc][0] = *(const f32x4*)p;
      pf[mt][kc][1] = *(const f32x4*)(p + 4);
    }
#pragma unroll
  for (int mt = 0; mt < 2; ++mt)
#pragma unroll
    for (int q = 0; q < 4; ++q)
      acc[mt][q] = (f32x4){bias[q], bias[q], bias[q], bias[q]};
#pragma unroll
  for (int kc = 0; kc < 4; ++kc)
#pragma unroll
    for (int mt = 0; mt < 2; ++mt) {
      f32x4 x0 = pf[mt][kc][0], x1 = pf[mt][kc][1];
      bf16x8 a;
      a[0] = (short)f2bf(x0[0]); a[1] = (short)f2bf(x0[1]);
      a[2] = (short)f2bf(x0[2]); a[3] = (short)f2bf(x0[3]);
      a[4] = (short)f2bf(x1[0]); a[5] = (short)f2bf(x1[1]);
      a[6] = (short)f2bf(x1[2]); a[7] = (short)f2bf(x1[3]);
#pragma unroll
      for (int q = 0; q < 4; ++q)
        acc[mt][q] = __builtin_amdgcn_mfma_f32_16x16x32_bf16(a, wfrag[q][kc], acc[mt][q], 0, 0, 0);
    }

  for (int t = 0; t < T_; ++t) {
    const int par = t & 1, np = par ^ 1;

    // ---- A) poll (last step's 2 out1 stores drain inside this wait)
    if (t > 0) {
      while (true) {
        u32x4 f = ld_flags(flrow);
        int ok = 1;
#pragma unroll
        for (int i = 0; i < 4; ++i) {
          u32 v = f[i];
          ok &= ((v & 255u) >= (u32)t) & (((v >> 8) & 255u) >= (u32)t) &
                (((v >> 16) & 255u) >= (u32)t) & (((v >> 24) & 255u) >= (u32)t);
        }
        if (ok) break;
      }
      __builtin_amdgcn_sched_barrier(0);
    }

    // ---- B) issue wx prefetch(t+1) + 12 REMOTE fragment loads; one drain;
    //          remote h-MFMAs (own-column MFMAs were done at last tail).
    const bool dowx = (t + 1 < T_);
    if (dowx) {
#pragma unroll
      for (int mt = 0; mt < 2; ++mt)
#pragma unroll
        for (int kc = 0; kc < 4; ++kc) {
          const float* p = wx + (size_t)(rb + mt * 16 + l15) * (T_ * N_)
                              + (size_t)(t + 1) * N_ + kc * 32 + koff;
          pf[mt][kc][0] = *(const f32x4*)p;
          pf[mt][kc][1] = *(const f32x4*)(p + 4);
        }
    }
    if (t > 0) {
      const u16* hxr = hx + ((size_t)par * RG_ + rg) * 8192;
      bf16x8 ah[2][8];   // only remote slots (pc != cg) are filled/used
#pragma unroll
      for (int mt = 0; mt < 2; ++mt)
#pragma unroll
        for (int kc2 = 0; kc2 < 8; ++kc2) {
          const int pc = kc2 >> 1, kcl = kc2 & 1;
          if (pc != cg)
            ah[mt][kc2] = ld16_dev(hxr + ((size_t)pc * 4 + (mt * 2 + kcl)) * 512
                                       + (size_t)lane * 8);
        }
      asm volatile("s_waitcnt vmcnt(0)" ::: "memory");   // remote + pf
      __builtin_amdgcn_sched_barrier(0);
#pragma unroll
      for (int kc2 = 0; kc2 < 8; ++kc2) {
        if ((kc2 >> 1) == cg) continue;   // uniform branch
#pragma unroll
        for (int q = 0; q < 4; ++q)
#pragma unroll
          for (int mt = 0; mt < 2; ++mt)
            acc[mt][q] = __builtin_amdgcn_mfma_f32_16x16x32_bf16(ah[mt][kc2], wfrag[q][4 + kc2], acc[mt][q], 0, 0, 0);
      }
    } else {
      asm volatile("s_waitcnt vmcnt(0)" ::: "memory");   // pf only (t==0)
    }

    // ---- C) LSTM cell -> hsh[np] (export dep first), then osh[par]
#pragma unroll
    for (int mt = 0; mt < 2; ++mt)
#pragma unroll
      for (int rr = 0; rr < 4; ++rr) {
        const float gi = acc[mt][0][rr];
        const float gf = acc[mt][1][rr];
        const float gg = acc[mt][2][rr];
        const float go = acc[mt][3][rr];
        const float c = sigm(gf) * creg[mt][rr] + sigm(gi) * tanh_(gg);
        creg[mt][rr] = c;
        const float h = sigm(go) * tanh_(c);
        const int row = mt * 16 + ((lane >> 4) << 2) + rr;
        hsh[np][row][w * 16 + l15] = f2bf(h);
        osh[par][row][w * 16 + l15] = h;
      }
    __syncthreads();

    // ---- D) export fragment -> drain -> flag; THEN out1 (off-path)
    {
      bf16x8 fv = *(const bf16x8*)&hsh[np][mtf * 16 + l15][kclf * 32 + koff];
      u16* dst = hx + ((size_t)np * RG_ + rg) * 8192 + (size_t)(cg * 4 + w) * 512
                    + (size_t)lane * 8;
      st16_dev(dst, fv);
      asm volatile("s_waitcnt vmcnt(0)" ::: "memory");   // export at L3
      if (lane == 0) st1_dev(myflag, (u32)(t + 1));
    }
#pragma unroll
    for (int i = 0; i < 2; ++i) {
      const int row = w * 8 + (lane >> 4) + i * 4;
      float* op = out1 + (size_t)(rb + row) * (T_ * H_) + (size_t)t * H_
                       + cg * 64 + l15 * 4;
      *(f32x4*)op = *(const f32x4*)&osh[par][row][l15 * 4];
    }

    // ---- E) producer-slack compute for t+1: acc = bias + wx(t+1) + own-h(t)
    if (dowx) {
#pragma unroll
      for (int mt = 0; mt < 2; ++mt)
#pragma unroll
        for (int q = 0; q < 4; ++q)
          acc[mt][q] = (f32x4){bias[q], bias[q], bias[q], bias[q]};
#pragma unroll
      for (int kc = 0; kc < 4; ++kc)
#pragma unroll
        for (int mt = 0; mt < 2; ++mt) {
          f32x4 x0 = pf[mt][kc][0], x1 = pf[mt][kc][1];
          bf16x8 a;
          a[0] = (short)f2bf(x0[0]); a[1] = (short)f2bf(x0[1]);
          a[2] = (short)f2bf(x0[2]); a[3] = (short)f2bf(x0[3]);
          a[4] = (short)f2bf(x1[0]); a[5] = (short)f2bf(x1[1]);
          a[6] = (short)f2bf(x1[2]); a[7] = (short)f2bf(x1[3]);
#pragma unroll
          for (int q = 0; q < 4; ++q)
            acc[mt][q] = __builtin_amdgcn_mfma_f32_16x16x32_bf16(a, wfrag[q][kc], acc[mt][q], 0, 0, 0);
        }
      // own-column h-MFMAs for step t+1 (reads hsh[np] = h(t), block-local)
#pragma unroll
      for (int kcl = 0; kcl < 2; ++kcl) {
        const int kc2 = cg * 2 + kcl;
        bf16x8 a0 = *(const bf16x8*)&hsh[np][l15][kcl * 32 + koff];
        bf16x8 a1 = *(const bf16x8*)&hsh[np][16 + l15][kcl * 32 + koff];
#pragma unroll
        for (int q = 0; q < 4; ++q) {
          acc[0][q] = __builtin_amdgcn_mfma_f32_16x16x32_bf16(a0, wfrag[q][4 + kc2], acc[0][q], 0, 0, 0);
          acc[1][q] = __builtin_amdgcn_mfma_f32_16x16x32_bf16(a1, wfrag[q][4 + kc2], acc[1][q], 0, 0, 0);
        }
      }
    }
  }
}

// ---------------------------------------------------------------- launch
extern "C" void kernel_launch(void* const* d_in, const int* in_sizes, int n_in,
                              void* d_out, int out_size, void* d_ws, size_t ws_size,
                              hipStream_t stream) {
  const float* x      = (const float*)d_in[0];
  const float* w_ih   = (const float*)d_in[1];
  const float* w_hh   = (const float*)d_in[2];
  const float* b_ih   = (const float*)d_in[3];
  const float* b_hh   = (const float*)d_in[4];
  const float* w_attn = (const float*)d_in[5];
  // d_in[6] (b_attn) provably unused (softmax shift invariance).

  float* out0 = (float*)d_out;                   // [B][T][N] input_weighted
  float* out1 = out0 + (size_t)B_ * T_ * N_;     // [B][T][H] input_encoded

  unsigned char* flags = (unsigned char*)d_ws;               // 8 KB (64x128B)
  u16* wpk  = (u16*)((char*)d_ws + 16384);                   // 768 KB
  u16* hx   = (u16*)((char*)d_ws + 16384 + 786432);          // 2 MB

  hipMemsetAsync(flags, 0, 8192, stream);
  prepack_kernel<<<dim3(1536), dim3(256), 0, stream>>>(w_ih, w_hh, wpk);
  attn_wx_kernel<<<dim3(B_), dim3(N_), 0, stream>>>(x, w_attn, out0);
  lstm_kernel<<<dim3(256), dim3(256), 0, stream>>>(out0, wpk, b_ih, b_hh,
                                                   out1, hx, flags);
}

// Round 11
// 882.126 us; speedup vs baseline: 1.8917x; 1.8917x over previous
//
#include <hip/hip_runtime.h>
#include <hip/hip_bf16.h>

// Attention-augmented LSTM encoder. B=2048, T=128, N=128, H=256.
// softmax shift-invariance -> attention time-invariant; w_h/w_c/b_attn dead.
//
// Round 11 = round 10 structure with the register-spill bug fixed.
// r10 indexed the persistent weight-fragment array with a RUNTIME value
// (wfrag[q][4 + cg*2 + kcl], cg = block colgroup) -> whole array demoted to
// scratch (VGPR 224->152, FETCH 0.46->3.58 GB, 2x slowdown). Fix: dispatch
// the own-column tail MFMAs through switch(cg) into a template<int CG>
// helper so ALL wfrag indices are compile-time literals.
// Structure (proven r9/r10): 256 blocks = 32-row x 64-hcol tiles; weights
// persistent in 192 VGPRs; relaxed sc0sc1 L3 exchange; per-wave u8 flags in
// one padded 128B line; own-column h-MFMAs + wx MFMAs in producer-slack tail;
// out1 stores after the flag publish.

#define B_ 2048
#define T_ 128
#define N_ 128
#define H_ 256
#define RG_ 64   // rowgroups of 32 rows

typedef float f32x4 __attribute__((ext_vector_type(4)));
typedef short bf16x8 __attribute__((ext_vector_type(8)));
typedef unsigned short u16;
typedef unsigned int u32;
typedef u32 u32x4 __attribute__((ext_vector_type(4)));

__device__ __forceinline__ u16 f2bf(float f) {
  unsigned int u = __float_as_uint(f);
  u += 0x7fffu + ((u >> 16) & 1u);   // RNE
  return (u16)(u >> 16);
}
__device__ __forceinline__ float sigm(float x) { return 1.f / (1.f + __expf(-x)); }
__device__ __forceinline__ float tanh_(float x) {
  float e = __expf(2.f * x);
  return 1.f - 2.f / (e + 1.f);
}

// device-coherent (L3) ops, relaxed (no cache-maintenance instructions)
__device__ __forceinline__ bf16x8 ld16_dev(const u16* p) {
  bf16x8 v;
  asm volatile("global_load_dwordx4 %0, %1, off sc0 sc1" : "=v"(v) : "v"(p));
  return v;
}
__device__ __forceinline__ void st16_dev(u16* p, bf16x8 v) {
  asm volatile("global_store_dwordx4 %0, %1, off sc0 sc1" :: "v"(p), "v"(v) : "memory");
}
__device__ __forceinline__ void st1_dev(unsigned char* p, u32 v) {
  asm volatile("global_store_byte %0, %1, off sc0 sc1" :: "v"(p), "v"(v) : "memory");
}
__device__ __forceinline__ u32x4 ld_flags(const unsigned char* p) {
  u32x4 f;
  asm volatile("global_load_dwordx4 %0, %1, off sc0 sc1\n\ts_waitcnt vmcnt(0)"
               : "=v"(f) : "v"(p) : "memory");
  return f;
}

// ---------------------------------------------------------------- kernel 1
__global__ __launch_bounds__(128) void attn_wx_kernel(
    const float* __restrict__ x, const float* __restrict__ w_attn,
    float* __restrict__ out0) {
  const int b = blockIdx.x;
  const int n = threadIdx.x;
  const float* xb = x + (size_t)b * (T_ * N_);
  __shared__ float red[N_];
  float xv[T_];
  float p = 0.f;
#pragma unroll
  for (int t = 0; t < T_; ++t) {
    xv[t] = xb[t * N_ + n];
    p += xv[t] * w_attn[2 * H_ + t];
  }
  red[n] = p;
  __syncthreads();
  float m = red[0];
  for (int i = 1; i < N_; ++i) m = fmaxf(m, red[i]);
  float e = __expf(p - m);
  __syncthreads();
  red[n] = e;
  __syncthreads();
  float s = 0.f;
  for (int i = 0; i < N_; ++i) s += red[i];
  const float a = e / s;
  float* ob = out0 + (size_t)b * (T_ * N_);
#pragma unroll
  for (int t = 0; t < T_; ++t) ob[t * N_ + n] = a * xv[t];
}

// ------------------------------------------------------- weight prepack
// frag(g16=0..15, q=0..3, kc=0..11) at ((g16*4+q)*12+kc)*512; elem j of lane l
// = W[q*256+g16*16+(l&15)][kc*32+((l>>4)<<3)+j], W = [w_ih | w_hh], K=384.
__global__ __launch_bounds__(256) void prepack_kernel(
    const float* __restrict__ w_ih, const float* __restrict__ w_hh,
    u16* __restrict__ wpk) {
  const int idx = blockIdx.x * 256 + threadIdx.x;  // 393216
  const int j = idx & 7;
  const int l = (idx >> 3) & 63;
  const int rest = idx >> 9;
  const int kc = rest % 12;
  const int wq = rest / 12;
  const int q = wq & 3;
  const int g16 = wq >> 2;
  const int grow = q * H_ + g16 * 16 + (l & 15);
  const int k = kc * 32 + ((l >> 4) << 3) + j;
  const float v = (k < N_) ? w_ih[(size_t)grow * N_ + k]
                           : w_hh[(size_t)grow * H_ + (k - N_)];
  wpk[idx] = f2bf(v);
}

// -------- own-column tail MFMAs: CG compile-time so wfrag idx is literal
template <int CG>
__device__ __forceinline__ void own_tail(
    f32x4 (&acc)[2][4], const bf16x8 (&wfrag)[4][12],
    const u16 (*hshnp)[72], int l15, int koff) {
#pragma unroll
  for (int kcl = 0; kcl < 2; ++kcl) {
    const int kc2 = CG * 2 + kcl;                 // literal
    bf16x8 a0 = *(const bf16x8*)&hshnp[l15][kcl * 32 + koff];
    bf16x8 a1 = *(const bf16x8*)&hshnp[16 + l15][kcl * 32 + koff];
#pragma unroll
    for (int q = 0; q < 4; ++q) {
      acc[0][q] = __builtin_amdgcn_mfma_f32_16x16x32_bf16(a0, wfrag[q][4 + kc2], acc[0][q], 0, 0, 0);
      acc[1][q] = __builtin_amdgcn_mfma_f32_16x16x32_bf16(a1, wfrag[q][4 + kc2], acc[1][q], 0, 0, 0);
    }
  }
}

// ---------------------------------------------------------------- kernel 2
__global__ __launch_bounds__(256, 1) void lstm_kernel(
    const float* __restrict__ wx,      // out0 f32 [B][T][N] (L3-resident)
    const u16* __restrict__ wpk,
    const float* __restrict__ b_ih, const float* __restrict__ b_hh,
    float* __restrict__ out1,          // f32 [B][T][H]
    u16* __restrict__ hx,              // [2][RG][16 frag][512 u16]
    unsigned char* __restrict__ flags) { // [RG][128B line; 16 u8 used]
  __shared__ u16 hsh[2][32][72];       // own 64 h-cols (bf16), ping-pong
  __shared__ float osh[2][32][68];     // h f32 staging for coalesced out1
  const int bid = blockIdx.x;
  const int rg = bid >> 2, cg = bid & 3;
  const int rb = rg * 32;
  const int tid  = threadIdx.x;
  const int w    = tid >> 6;           // wave 0..3
  const int lane = tid & 63;
  const int l15  = lane & 15;
  const int koff = (lane >> 4) << 3;
  const int g16  = cg * 4 + w;
  const int hcol = cg * 64 + w * 16 + l15;

  // persistent weights: 48 frags = 192 VGPRs (compile-time indexed ONLY)
  bf16x8 wfrag[4][12];
  {
    const u16* wp = wpk + (size_t)(g16 * 48) * 512 + (size_t)lane * 8;
#pragma unroll
    for (int q = 0; q < 4; ++q)
#pragma unroll
      for (int kc = 0; kc < 12; ++kc)
        wfrag[q][kc] = *(const bf16x8*)(wp + (size_t)(q * 12 + kc) * 512);
  }
  float bias[4];
#pragma unroll
  for (int q = 0; q < 4; ++q)
    bias[q] = b_ih[q * H_ + hcol] + b_hh[q * H_ + hcol];
  float creg[2][4] = {};

  unsigned char* flrow  = flags + (size_t)rg * 128;
  unsigned char* myflag = flrow + cg * 4 + w;
  const int mtf = w >> 1, kclf = w & 1;   // fragment this wave exports

  // ---- prologue: wx(0) -> pf; acc = bias + wx-part(0)  (h(-1)=0)
  f32x4 pf[2][4][2];
  f32x4 acc[2][4];
#pragma unroll
  for (int mt = 0; mt < 2; ++mt)
#pragma unroll
    for (int kc = 0; kc < 4; ++kc) {
      const float* p = wx + (size_t)(rb + mt * 16 + l15) * (T_ * N_) + kc * 32 + koff;
      pf[mt][kc][0] = *(const f32x4*)p;
      pf[mt][kc][1] = *(const f32x4*)(p + 4);
    }
#pragma unroll
  for (int mt = 0; mt < 2; ++mt)
#pragma unroll
    for (int q = 0; q < 4; ++q)
      acc[mt][q] = (f32x4){bias[q], bias[q], bias[q], bias[q]};
#pragma unroll
  for (int kc = 0; kc < 4; ++kc)
#pragma unroll
    for (int mt = 0; mt < 2; ++mt) {
      f32x4 x0 = pf[mt][kc][0], x1 = pf[mt][kc][1];
      bf16x8 a;
      a[0] = (short)f2bf(x0[0]); a[1] = (short)f2bf(x0[1]);
      a[2] = (short)f2bf(x0[2]); a[3] = (short)f2bf(x0[3]);
      a[4] = (short)f2bf(x1[0]); a[5] = (short)f2bf(x1[1]);
      a[6] = (short)f2bf(x1[2]); a[7] = (short)f2bf(x1[3]);
#pragma unroll
      for (int q = 0; q < 4; ++q)
        acc[mt][q] = __builtin_amdgcn_mfma_f32_16x16x32_bf16(a, wfrag[q][kc], acc[mt][q], 0, 0, 0);
    }

  for (int t = 0; t < T_; ++t) {
    const int par = t & 1, np = par ^ 1;

    // ---- A) poll (last step's 2 out1 stores drain inside this wait)
    if (t > 0) {
      while (true) {
        u32x4 f = ld_flags(flrow);
        int ok = 1;
#pragma unroll
        for (int i = 0; i < 4; ++i) {
          u32 v = f[i];
          ok &= ((v & 255u) >= (u32)t) & (((v >> 8) & 255u) >= (u32)t) &
                (((v >> 16) & 255u) >= (u32)t) & (((v >> 24) & 255u) >= (u32)t);
        }
        if (ok) break;
      }
      __builtin_amdgcn_sched_barrier(0);
    }

    // ---- B) issue wx prefetch(t+1) + 12 REMOTE fragment loads; one drain;
    //          remote h-MFMAs (own-column MFMAs were done at last tail).
    const bool dowx = (t + 1 < T_);
    if (dowx) {
#pragma unroll
      for (int mt = 0; mt < 2; ++mt)
#pragma unroll
        for (int kc = 0; kc < 4; ++kc) {
          const float* p = wx + (size_t)(rb + mt * 16 + l15) * (T_ * N_)
                              + (size_t)(t + 1) * N_ + kc * 32 + koff;
          pf[mt][kc][0] = *(const f32x4*)p;
          pf[mt][kc][1] = *(const f32x4*)(p + 4);
        }
    }
    if (t > 0) {
      const u16* hxr = hx + ((size_t)par * RG_ + rg) * 8192;
      bf16x8 ah[2][8];   // only remote slots (pc != cg) are filled/used
#pragma unroll
      for (int mt = 0; mt < 2; ++mt)
#pragma unroll
        for (int kc2 = 0; kc2 < 8; ++kc2) {
          const int pc = kc2 >> 1, kcl = kc2 & 1;
          if (pc != cg)
            ah[mt][kc2] = ld16_dev(hxr + ((size_t)pc * 4 + (mt * 2 + kcl)) * 512
                                       + (size_t)lane * 8);
        }
      asm volatile("s_waitcnt vmcnt(0)" ::: "memory");   // remote + pf
      __builtin_amdgcn_sched_barrier(0);
#pragma unroll
      for (int kc2 = 0; kc2 < 8; ++kc2) {
        if ((kc2 >> 1) == cg) continue;   // uniform branch; indices literal
#pragma unroll
        for (int q = 0; q < 4; ++q)
#pragma unroll
          for (int mt = 0; mt < 2; ++mt)
            acc[mt][q] = __builtin_amdgcn_mfma_f32_16x16x32_bf16(ah[mt][kc2], wfrag[q][4 + kc2], acc[mt][q], 0, 0, 0);
      }
    } else {
      asm volatile("s_waitcnt vmcnt(0)" ::: "memory");   // pf only (t==0)
    }

    // ---- C) LSTM cell -> hsh[np] (export dep first), then osh[par]
#pragma unroll
    for (int mt = 0; mt < 2; ++mt)
#pragma unroll
      for (int rr = 0; rr < 4; ++rr) {
        const float gi = acc[mt][0][rr];
        const float gf = acc[mt][1][rr];
        const float gg = acc[mt][2][rr];
        const float go = acc[mt][3][rr];
        const float c = sigm(gf) * creg[mt][rr] + sigm(gi) * tanh_(gg);
        creg[mt][rr] = c;
        const float h = sigm(go) * tanh_(c);
        const int row = mt * 16 + ((lane >> 4) << 2) + rr;
        hsh[np][row][w * 16 + l15] = f2bf(h);
        osh[par][row][w * 16 + l15] = h;
      }
    __syncthreads();

    // ---- D) export fragment -> drain -> flag; THEN out1 (off-path)
    {
      bf16x8 fv = *(const bf16x8*)&hsh[np][mtf * 16 + l15][kclf * 32 + koff];
      u16* dst = hx + ((size_t)np * RG_ + rg) * 8192 + (size_t)(cg * 4 + w) * 512
                    + (size_t)lane * 8;
      st16_dev(dst, fv);
      asm volatile("s_waitcnt vmcnt(0)" ::: "memory");   // export at L3
      if (lane == 0) st1_dev(myflag, (u32)(t + 1));
    }
#pragma unroll
    for (int i = 0; i < 2; ++i) {
      const int row = w * 8 + (lane >> 4) + i * 4;
      float* op = out1 + (size_t)(rb + row) * (T_ * H_) + (size_t)t * H_
                       + cg * 64 + l15 * 4;
      *(f32x4*)op = *(const f32x4*)&osh[par][row][l15 * 4];
    }

    // ---- E) producer-slack compute for t+1: acc = bias + wx(t+1) + own-h(t)
    if (dowx) {
#pragma unroll
      for (int mt = 0; mt < 2; ++mt)
#pragma unroll
        for (int q = 0; q < 4; ++q)
          acc[mt][q] = (f32x4){bias[q], bias[q], bias[q], bias[q]};
#pragma unroll
      for (int kc = 0; kc < 4; ++kc)
#pragma unroll
        for (int mt = 0; mt < 2; ++mt) {
          f32x4 x0 = pf[mt][kc][0], x1 = pf[mt][kc][1];
          bf16x8 a;
          a[0] = (short)f2bf(x0[0]); a[1] = (short)f2bf(x0[1]);
          a[2] = (short)f2bf(x0[2]); a[3] = (short)f2bf(x0[3]);
          a[4] = (short)f2bf(x1[0]); a[5] = (short)f2bf(x1[1]);
          a[6] = (short)f2bf(x1[2]); a[7] = (short)f2bf(x1[3]);
#pragma unroll
          for (int q = 0; q < 4; ++q)
            acc[mt][q] = __builtin_amdgcn_mfma_f32_16x16x32_bf16(a, wfrag[q][kc], acc[mt][q], 0, 0, 0);
        }
      // own-column h-MFMAs for t+1 from hsh[np]=h(t); CG made compile-time
      switch (cg) {
        case 0: own_tail<0>(acc, wfrag, hsh[np], l15, koff); break;
        case 1: own_tail<1>(acc, wfrag, hsh[np], l15, koff); break;
        case 2: own_tail<2>(acc, wfrag, hsh[np], l15, koff); break;
        default: own_tail<3>(acc, wfrag, hsh[np], l15, koff); break;
      }
    }
  }
}

// ---------------------------------------------------------------- launch
extern "C" void kernel_launch(void* const* d_in, const int* in_sizes, int n_in,
                              void* d_out, int out_size, void* d_ws, size_t ws_size,
                              hipStream_t stream) {
  const float* x      = (const float*)d_in[0];
  const float* w_ih   = (const float*)d_in[1];
  const float* w_hh   = (const float*)d_in[2];
  const float* b_ih   = (const float*)d_in[3];
  const float* b_hh   = (const float*)d_in[4];
  const float* w_attn = (const float*)d_in[5];
  // d_in[6] (b_attn) provably unused (softmax shift invariance).

  float* out0 = (float*)d_out;                   // [B][T][N] input_weighted
  float* out1 = out0 + (size_t)B_ * T_ * N_;     // [B][T][H] input_encoded

  unsigned char* flags = (unsigned char*)d_ws;               // 8 KB (64x128B)
  u16* wpk  = (u16*)((char*)d_ws + 16384);                   // 768 KB
  u16* hx   = (u16*)((char*)d_ws + 16384 + 786432);          // 2 MB

  hipMemsetAsync(flags, 0, 8192, stream);
  prepack_kernel<<<dim3(1536), dim3(256), 0, stream>>>(w_ih, w_hh, wpk);
  attn_wx_kernel<<<dim3(B_), dim3(N_), 0, stream>>>(x, w_attn, out0);
  lstm_kernel<<<dim3(256), dim3(256), 0, stream>>>(out0, wpk, b_ih, b_hh,
                                                   out1, hx, flags);
}